// Round 12
// baseline (1973.609 us; speedup 1.0000x reference)
//
#include <hip/hip_runtime.h>
#include <hip/hip_bf16.h>
#include <stdint.h>

// Problem constants
#define NN 20000      // nodes
#define NE 640000     // edges
#define HID 512
#define MID 4352
#define VOC 8192

typedef __attribute__((ext_vector_type(16))) float f32x16;
typedef __attribute__((ext_vector_type(8))) short bf16x8;

__device__ __forceinline__ unsigned short f2bf(float f) {
  unsigned int u = __float_as_uint(f);
  u += 0x7fffu + ((u >> 16) & 1u);   // round-to-nearest-even
  return (unsigned short)(u >> 16);
}

// ---------------- detect edge_index storage width ----------------
__global__ void k_detect64(const int* __restrict__ ei32, int* __restrict__ flag) {
  __shared__ int any_nz;
  if (threadIdx.x == 0) any_nz = 0;
  __syncthreads();
  int v = ei32[2 * threadIdx.x + 1];
  if (v != 0) atomicOr(&any_nz, 1);
  __syncthreads();
  if (threadIdx.x == 0) *flag = (any_nz == 0) ? 1 : 0;  // 1 => int64 layout
}

__global__ void k_zero_i32(int* __restrict__ p, int n) {
  int i = blockIdx.x * blockDim.x + threadIdx.x;
  if (i < n) p[i] = 0;
}

__global__ void k_count(const int* __restrict__ ei, const int* __restrict__ flag,
                        int* __restrict__ deg) {
  int e = blockIdx.x * blockDim.x + threadIdx.x;
  if (e >= NE) return;
  int is64 = *flag;
  int d = is64 ? ei[2 * (NE + e)] : ei[NE + e];
  if ((unsigned)d >= NN) return;
  atomicAdd(&deg[d], 1);
}

__global__ __launch_bounds__(1024)
void k_scan(const int* __restrict__ deg, int* __restrict__ offs, int* __restrict__ cursor) {
  __shared__ int part[1024];
  const int t = threadIdx.x;
  const int CH = (NN + 1023) / 1024;  // 20
  const int base = t * CH;
  int s = 0;
  for (int i = 0; i < CH; ++i) { int idx = base + i; if (idx < NN) s += deg[idx]; }
  part[t] = s;
  __syncthreads();
  for (int off = 1; off < 1024; off <<= 1) {
    int v = (t >= off) ? part[t - off] : 0;
    __syncthreads();
    part[t] += v;
    __syncthreads();
  }
  int run = (t == 0) ? 0 : part[t - 1];  // exclusive prefix
  for (int i = 0; i < CH; ++i) {
    int idx = base + i;
    if (idx < NN) { offs[idx] = run; cursor[idx] = run; run += deg[idx]; }
  }
}

__global__ void k_fill(const int* __restrict__ ei, const int* __restrict__ flag,
                       int* __restrict__ cursor, int* __restrict__ csr) {
  int e = blockIdx.x * blockDim.x + threadIdx.x;
  if (e >= NE) return;
  int is64 = *flag;
  int s, d;
  if (is64) { s = ei[2 * e]; d = ei[2 * (NE + e)]; }
  else      { s = ei[e];     d = ei[NE + e]; }
  if ((unsigned)s >= NN || (unsigned)d >= NN) return;
  int pos = atomicAdd(&cursor[d], 1);
  csr[pos] = s;
}

__global__ void k_f32_to_bf16(const float4* __restrict__ src, uint2* __restrict__ dst, int n4) {
  int i = blockIdx.x * blockDim.x + threadIdx.x;
  int stride = gridDim.x * blockDim.x;
  for (; i < n4; i += stride) {
    float4 v = src[i];
    uint2 o;
    o.x = (unsigned)f2bf(v.x) | ((unsigned)f2bf(v.y) << 16);
    o.y = (unsigned)f2bf(v.z) | ((unsigned)f2bf(v.w) << 16);
    dst[i] = o;
  }
}

// ---------------- fused gather: hb = bf16(x_i + sum bf16(x_j)) ----------------
__global__ __launch_bounds__(256)
void k_gather2(const float4* __restrict__ x4, const uint4* __restrict__ xb4,
               const int* __restrict__ offs, const int* __restrict__ deg,
               const int* __restrict__ csr, uint4* __restrict__ hb4) {
  const int wid = blockIdx.x * (blockDim.x >> 6) + (threadIdx.x >> 6);
  if (wid >= NN) return;
  const int lane = threadIdx.x & 63;
  float4 s0 = x4[(long long)wid * 128 + lane * 2];
  float4 s1 = x4[(long long)wid * 128 + lane * 2 + 1];
  float a0 = s0.x, a1 = s0.y, a2 = s0.z, a3 = s0.w;
  float a4 = s1.x, a5 = s1.y, a6 = s1.z, a7 = s1.w;
  const int beg = offs[wid];
  const int dc  = deg[wid];
  for (int j = 0; j < dc; ++j) {
    int s = csr[beg + j];
    uint4 v = xb4[(long long)s * 64 + lane];
    a0 += __uint_as_float(v.x << 16); a1 += __uint_as_float(v.x & 0xffff0000u);
    a2 += __uint_as_float(v.y << 16); a3 += __uint_as_float(v.y & 0xffff0000u);
    a4 += __uint_as_float(v.z << 16); a5 += __uint_as_float(v.z & 0xffff0000u);
    a6 += __uint_as_float(v.w << 16); a7 += __uint_as_float(v.w & 0xffff0000u);
  }
  uint4 o;
  o.x = (unsigned)f2bf(a0) | ((unsigned)f2bf(a1) << 16);
  o.y = (unsigned)f2bf(a2) | ((unsigned)f2bf(a3) << 16);
  o.z = (unsigned)f2bf(a4) | ((unsigned)f2bf(a5) << 16);
  o.w = (unsigned)f2bf(a6) | ((unsigned)f2bf(a7) << 16);
  hb4[(long long)wid * 64 + lane] = o;
}

// =================== 256x256 8-phase bf16 GEMM — 32x32x16 MFMA ===================
// C[M,N] = A[M,K] * B[N,K]^T + bias.  BK=64, 512 thr = 8 waves (2Mx4N),
// per-wave 128x64 = 4x2 frags of 32x32. R8's exact proven skeleton (staging
// stagger, VMC(2) at P4/P8, seg-swizzle both-sides -> 0 conflicts), only the
// MFMA shape changes: 32 x mfma_32x32x16 per K-tile per wave instead of
// 128 x mfma_16x16x32 (same FLOPs, ~17% fewer MFMA-pipe cycles: 2495 vs
// 2075 TF ubench). LDS read volume unchanged (operand bytes invariant).
// A/B frag: row=lane&31, k=(lane>>5)*8 (8 contiguous bf16 = 1 b128).
// C/D frag (HW-verified m74/m101): col=lane&31, row=(reg&3)+8*(reg>>2)+4*(lane>>5).

#define SBAR  __builtin_amdgcn_s_barrier()
#define SCHB  __builtin_amdgcn_sched_barrier(0)
#define VMC(n) asm volatile("s_waitcnt vmcnt(" #n ")" ::: "memory")
#define PRIO1 __builtin_amdgcn_s_setprio(1)
#define PRIO0 __builtin_amdgcn_s_setprio(0)

// read A quad qm (64 rows = 2 frags x 4 ksteps)
#define READ_A(qm, bufc) \
  _Pragma("unroll") for (int f_ = 0; f_ < 2; ++f_) \
    _Pragma("unroll") for (int kk_ = 0; kk_ < 4; ++kk_) \
      aF[f_][kk_] = *(const bf16x8*)((bufc) + aBase + (qm) * 8192 + f_ * 4096 + sgk[kk_]);

// read B quad qn (32 cols = 1 frag x 4 ksteps)
#define READ_B(qn, bufc, DST) \
  _Pragma("unroll") for (int kk_ = 0; kk_ < 4; ++kk_) \
    DST[kk_] = *(const bf16x8*)((bufc) + 32768 + bBase + (qn) * 4096 + sgk[kk_]);

// 8 MFMA (2 row-frags x 4 ksteps) for quad (qm, qn)
#define MFMA_Q(qm, qn, BQ) \
  _Pragma("unroll") for (int kk_ = 0; kk_ < 4; ++kk_) { \
    acc[(qm)*2+0][qn] = __builtin_amdgcn_mfma_f32_32x32x16_bf16( \
        aF[0][kk_], BQ[kk_], acc[(qm)*2+0][qn], 0, 0, 0); \
    acc[(qm)*2+1][qn] = __builtin_amdgcn_mfma_f32_32x32x16_bf16( \
        aF[1][kk_], BQ[kk_], acc[(qm)*2+1][qn], 0, 0, 0); \
  }

#define STAGE_A(bufc, kt, ha) \
  _Pragma("unroll") for (int j_ = 0; j_ < 2; ++j_) { \
    int rl_ = (ha) * 128 + (w * 2 + j_) * 8 + stSub; \
    int gr_ = aRow0 + rl_; if (gr_ > Mm1) gr_ = Mm1; \
    __builtin_amdgcn_global_load_lds( \
      (const __attribute__((address_space(1))) void*)(A + (long long)gr_ * K + (kt) * 64 + stSeg8), \
      (__attribute__((address_space(3))) void*)((bufc) + (ha) * 16384 + (w * 2 + j_) * 1024), \
      16, 0, 0); \
  }

#define STAGE_B(bufc, kt, ha) \
  _Pragma("unroll") for (int j_ = 0; j_ < 2; ++j_) { \
    int rl_ = (ha) * 128 + (w * 2 + j_) * 8 + stSub; \
    int gr_ = bRow0 + rl_; \
    __builtin_amdgcn_global_load_lds( \
      (const __attribute__((address_space(1))) void*)(B + (long long)gr_ * K + (kt) * 64 + stSeg8), \
      (__attribute__((address_space(3))) void*)((bufc) + 32768 + (ha) * 16384 + (w * 2 + j_) * 1024), \
      16, 0, 0); \
  }

template<bool OUT_BF16>
__global__ __launch_bounds__(512, 2)
void k_gemm256(const unsigned short* __restrict__ A,   // [M,K] bf16
               const unsigned short* __restrict__ B,   // [N,K] bf16
               const float* __restrict__ bias,         // [N]
               void* __restrict__ C,                   // [M,N] f32 or bf16
               int M, int N, int K)
{
  __shared__ __align__(16) char lds[131072];   // 2 x (A 32KB + B 32KB)

  const int tid  = threadIdx.x;
  const int lane = tid & 63;
  const int w    = tid >> 6;       // 0..7
  const int wr   = w >> 2;         // 0..1  (M)
  const int wc   = w & 3;          // 0..3  (N)

  // grid mapping: bn-chunk per XCD if possible, else m204 bijective swizzle
  const int nwg  = gridDim.x * gridDim.y;
  const int orig = blockIdx.y * gridDim.x + blockIdx.x;
  int bn, bm;
  if ((gridDim.x & 7) == 0 && (nwg & 7) == 0) {
    const int xcd = orig & 7;
    const int j   = orig >> 3;
    const int chunk = gridDim.x >> 3;
    bn = xcd * chunk + (j % chunk);
    bm = j / chunk;
  } else {
    const int q = nwg >> 3, r = nwg & 7;
    const int xcd = orig & 7, land = orig >> 3;
    const int nid = (xcd < r ? xcd * (q + 1) : r * (q + 1) + (xcd - r) * q) + land;
    bn = nid % gridDim.x;
    bm = nid / gridDim.x;
  }

  // per-lane constants
  const int l31 = lane & 31;
  const int lhi = lane >> 5;                      // 0..1
  const int l7  = lane & 7;
  int sgk[4];
#pragma unroll
  for (int kk_ = 0; kk_ < 4; ++kk_)
    sgk[kk_] = ((kk_ * 2 + lhi) ^ l7) * 16;       // swizzled seg byte offsets
  const int aBase = (wr * 128 + l31) * 128;       // A read base (bytes)
  const int bBase = (wc * 64  + l31) * 128;       // B read base (bytes)
  const int stSub  = lane >> 3;                   // 0..7
  const int stSeg8 = ((lane & 7) ^ stSub) * 8;    // pre-swizzled source seg (elems)
  const int aRow0 = bm * 256;
  const int bRow0 = bn * 256;
  const int Mm1 = M - 1;

  char* lb0 = (char*)lds;            // even K-tiles
  char* lb1 = (char*)lds + 65536;    // odd K-tiles

  f32x16 acc[4][2] = {};             // 4 row-frags x 2 col-frags of 32x32
  bf16x8 aF[2][4], bFa[4], bFb[4];

  const int nkt = K >> 6;            // 64-wide K tiles (even count for 512/4352)
  const int nit = nkt >> 1;

  // prologue: tile0 full + tile1.A-h0 (R8 invariant)
  STAGE_A(lb0, 0, 0); STAGE_A(lb0, 0, 1); STAGE_B(lb0, 0, 0); STAGE_B(lb0, 0, 1);
  STAGE_A(lb1, 1, 0);
  VMC(2);
  SBAR;

  for (int i = 0; i < nit; ++i) {
    const int ktO = 2 * i + 1;
    int ktE2 = 2 * i + 2; if (ktE2 >= nkt) ktE2 = nkt - 1;  // clamped junk on last iter
    int ktO2 = 2 * i + 3; if (ktO2 >= nkt) ktO2 = nkt - 1;
    // P1: tile E quad(0,0)
    READ_A(0, lb0); READ_B(0, lb0, bFa);
    STAGE_A(lb1, ktO, 1);
    SBAR; PRIO1; MFMA_Q(0, 0, bFa); PRIO0; SCHB; SBAR;
    // P2: quad(0,1)
    READ_B(1, lb0, bFb);
    STAGE_B(lb1, ktO, 0);
    SBAR; PRIO1; MFMA_Q(0, 1, bFb); PRIO0; SCHB; SBAR;
    // P3: quad(1,1)
    READ_A(1, lb0);
    STAGE_B(lb1, ktO, 1);
    SBAR; PRIO1; MFMA_Q(1, 1, bFb); PRIO0; SCHB; SBAR;
    // P4: quad(1,0); VMC(2) completes tile O staging
    STAGE_A(lb0, ktE2, 0);
    SBAR; PRIO1; MFMA_Q(1, 0, bFa); PRIO0; SCHB; VMC(2); SBAR;
    // P5: tile O quad(0,0)
    READ_A(0, lb1); READ_B(0, lb1, bFa);
    STAGE_A(lb0, ktE2, 1);
    SBAR; PRIO1; MFMA_Q(0, 0, bFa); PRIO0; SCHB; SBAR;
    // P6: quad(0,1)
    READ_B(1, lb1, bFb);
    STAGE_B(lb0, ktE2, 0);
    SBAR; PRIO1; MFMA_Q(0, 1, bFb); PRIO0; SCHB; SBAR;
    // P7: quad(1,1)
    READ_A(1, lb1);
    STAGE_B(lb0, ktE2, 1);
    SBAR; PRIO1; MFMA_Q(1, 1, bFb); PRIO0; SCHB; SBAR;
    // P8: quad(1,0); VMC(2) completes tile E' staging
    STAGE_A(lb1, ktO2, 0);
    SBAR; PRIO1; MFMA_Q(1, 0, bFa); PRIO0; SCHB; VMC(2); SBAR;
  }

  // epilogue: C[row, col] = acc + bias; 32x32 C/D layout:
  // col = lane&31, row = (reg&3) + 8*(reg>>2) + 4*(lane>>5)
#pragma unroll
  for (int jn = 0; jn < 2; ++jn) {
    const int col = bn * 256 + wc * 64 + jn * 32 + l31;
    const float bv = bias[col];
#pragma unroll
    for (int im = 0; im < 4; ++im) {
      const int row0 = bm * 256 + wr * 128 + im * 32 + 4 * lhi;
#pragma unroll
      for (int reg = 0; reg < 16; ++reg) {
        const int row = row0 + (reg & 3) + 8 * (reg >> 2);
        if (row < M) {
          const float v = acc[im][jn][reg] + bv;
          if (OUT_BF16)
            __builtin_nontemporal_store(f2bf(v), &((unsigned short*)C)[(long long)row * N + col]);
          else
            __builtin_nontemporal_store(v, &((float*)C)[(long long)row * N + col]);
        }
      }
    }
  }
}

extern "C" void kernel_launch(void* const* d_in, const int* in_sizes, int n_in,
                              void* d_out, int out_size, void* d_ws, size_t ws_size,
                              hipStream_t stream) {
  const float* x  = (const float*)d_in[0];
  const int*   ei = (const int*)d_in[1];      // int32 or int64 — detected on device
  const float* W1 = (const float*)d_in[2];
  const float* b1 = (const float*)d_in[3];
  const float* W2 = (const float*)d_in[4];
  const float* b2 = (const float*)d_in[5];
  float* out = (float*)d_out;
  char* ws = (char*)d_ws;

  // workspace layout (bytes, 16B-aligned)
  int* flag            = (int*)(ws + 0);                    // 256
  int* deg             = (int*)(ws + 256);                  // 80,000
  int* offs            = (int*)(ws + 80256);                // 80,000
  int* cursor          = (int*)(ws + 160256);               // 80,000
  int* csr             = (int*)(ws + 240256);               // 2,560,000
  unsigned short* xb   = (unsigned short*)(ws + 2800256);   // 20,480,000
  unsigned short* hb   = (unsigned short*)(ws + 23280256);  // 20,480,000
  unsigned short* w1b  = (unsigned short*)(ws + 43760256);  //  4,456,448
  unsigned short* w2b  = (unsigned short*)(ws + 48216704);  // 71,303,168
  const size_t h1_off  = 119519872;
  if (ws_size < h1_off + (size_t)256 * MID * 2) return;
  unsigned short* h1b  = (unsigned short*)(ws + h1_off);

  long long rem = (long long)ws_size - (long long)h1_off;
  int max_rows = (int)(rem / ((long long)MID * 2));
  max_rows = (max_rows / 256) * 256;
  if (max_rows > 20224) max_rows = 20224;

  // 0) detect edge_index width
  k_detect64<<<1, 256, 0, stream>>>(ei, flag);

  // 1) CSR build
  k_zero_i32<<<(NN + 255) / 256, 256, 0, stream>>>(deg, NN);
  k_count<<<(NE + 255) / 256, 256, 0, stream>>>(ei, flag, deg);
  k_scan<<<1, 1024, 0, stream>>>(deg, offs, cursor);
  k_fill<<<(NE + 255) / 256, 256, 0, stream>>>(ei, flag, cursor, csr);

  // 2) conversions to bf16 (x first: gather depends on it)
  k_f32_to_bf16<<<2048, 256, 0, stream>>>((const float4*)x,  (uint2*)xb,  NN * HID / 4);
  k_f32_to_bf16<<<1024, 256, 0, stream>>>((const float4*)W1, (uint2*)w1b, MID * HID / 4);
  k_f32_to_bf16<<<2048, 256, 0, stream>>>((const float4*)W2, (uint2*)w2b, VOC * MID / 4);

  // 3) fused gather: hb = bf16(x_i + sum_j bf16(x_j))
  k_gather2<<<(NN + 3) / 4, 256, 0, stream>>>((const float4*)x, (const uint4*)xb,
                                              offs, deg, csr, (uint4*)hb);

  // 4+5) chunked GEMM1 -> GEMM2 over M (usually a single chunk)
  for (int r0 = 0; r0 < NN; r0 += max_rows) {
    int mrows = (NN - r0 < max_rows) ? (NN - r0) : max_rows;
    dim3 g1(MID / 256, (mrows + 255) / 256);
    k_gemm256<true><<<g1, 512, 0, stream>>>(hb + (size_t)r0 * HID, w1b, b1,
                                            (void*)h1b, mrows, MID, HID);
    dim3 g2(VOC / 256, (mrows + 255) / 256);
    k_gemm256<false><<<g2, 512, 0, stream>>>(h1b, w2b, b2,
                                             (void*)(out + (size_t)r0 * VOC), mrows, VOC, MID);
  }
}

// Round 13
// 1787.104 us; speedup vs baseline: 1.1044x; 1.1044x over previous
//
#include <hip/hip_runtime.h>
#include <hip/hip_bf16.h>
#include <stdint.h>

// Problem constants
#define NN 20000      // nodes
#define NE 640000     // edges
#define HID 512
#define MID 4352
#define VOC 8192

typedef __attribute__((ext_vector_type(4))) float f32x4;
typedef __attribute__((ext_vector_type(8))) short bf16x8;

__device__ __forceinline__ unsigned short f2bf(float f) {
  unsigned int u = __float_as_uint(f);
  u += 0x7fffu + ((u >> 16) & 1u);   // round-to-nearest-even
  return (unsigned short)(u >> 16);
}

// ---------------- detect edge_index storage width ----------------
__global__ void k_detect64(const int* __restrict__ ei32, int* __restrict__ flag) {
  __shared__ int any_nz;
  if (threadIdx.x == 0) any_nz = 0;
  __syncthreads();
  int v = ei32[2 * threadIdx.x + 1];
  if (v != 0) atomicOr(&any_nz, 1);
  __syncthreads();
  if (threadIdx.x == 0) *flag = (any_nz == 0) ? 1 : 0;  // 1 => int64 layout
}

__global__ void k_zero_i32(int* __restrict__ p, int n) {
  int i = blockIdx.x * blockDim.x + threadIdx.x;
  if (i < n) p[i] = 0;
}

__global__ void k_count(const int* __restrict__ ei, const int* __restrict__ flag,
                        int* __restrict__ deg) {
  int e = blockIdx.x * blockDim.x + threadIdx.x;
  if (e >= NE) return;
  int is64 = *flag;
  int d = is64 ? ei[2 * (NE + e)] : ei[NE + e];
  if ((unsigned)d >= NN) return;
  atomicAdd(&deg[d], 1);
}

__global__ __launch_bounds__(1024)
void k_scan(const int* __restrict__ deg, int* __restrict__ offs, int* __restrict__ cursor) {
  __shared__ int part[1024];
  const int t = threadIdx.x;
  const int CH = (NN + 1023) / 1024;  // 20
  const int base = t * CH;
  int s = 0;
  for (int i = 0; i < CH; ++i) { int idx = base + i; if (idx < NN) s += deg[idx]; }
  part[t] = s;
  __syncthreads();
  for (int off = 1; off < 1024; off <<= 1) {
    int v = (t >= off) ? part[t - off] : 0;
    __syncthreads();
    part[t] += v;
    __syncthreads();
  }
  int run = (t == 0) ? 0 : part[t - 1];  // exclusive prefix
  for (int i = 0; i < CH; ++i) {
    int idx = base + i;
    if (idx < NN) { offs[idx] = run; cursor[idx] = run; run += deg[idx]; }
  }
}

__global__ void k_fill(const int* __restrict__ ei, const int* __restrict__ flag,
                       int* __restrict__ cursor, int* __restrict__ csr) {
  int e = blockIdx.x * blockDim.x + threadIdx.x;
  if (e >= NE) return;
  int is64 = *flag;
  int s, d;
  if (is64) { s = ei[2 * e]; d = ei[2 * (NE + e)]; }
  else      { s = ei[e];     d = ei[NE + e]; }
  if ((unsigned)s >= NN || (unsigned)d >= NN) return;
  int pos = atomicAdd(&cursor[d], 1);
  csr[pos] = s;
}

__global__ void k_f32_to_bf16(const float4* __restrict__ src, uint2* __restrict__ dst, int n4) {
  int i = blockIdx.x * blockDim.x + threadIdx.x;
  int stride = gridDim.x * blockDim.x;
  for (; i < n4; i += stride) {
    float4 v = src[i];
    uint2 o;
    o.x = (unsigned)f2bf(v.x) | ((unsigned)f2bf(v.y) << 16);
    o.y = (unsigned)f2bf(v.z) | ((unsigned)f2bf(v.w) << 16);
    dst[i] = o;
  }
}

// ---------------- fused gather: hb = bf16(x_i + sum bf16(x_j)) ----------------
__global__ __launch_bounds__(256)
void k_gather2(const float4* __restrict__ x4, const uint4* __restrict__ xb4,
               const int* __restrict__ offs, const int* __restrict__ deg,
               const int* __restrict__ csr, uint4* __restrict__ hb4) {
  const int wid = blockIdx.x * (blockDim.x >> 6) + (threadIdx.x >> 6);
  if (wid >= NN) return;
  const int lane = threadIdx.x & 63;
  float4 s0 = x4[(long long)wid * 128 + lane * 2];
  float4 s1 = x4[(long long)wid * 128 + lane * 2 + 1];
  float a0 = s0.x, a1 = s0.y, a2 = s0.z, a3 = s0.w;
  float a4 = s1.x, a5 = s1.y, a6 = s1.z, a7 = s1.w;
  const int beg = offs[wid];
  const int dc  = deg[wid];
  for (int j = 0; j < dc; ++j) {
    int s = csr[beg + j];
    uint4 v = xb4[(long long)s * 64 + lane];
    a0 += __uint_as_float(v.x << 16); a1 += __uint_as_float(v.x & 0xffff0000u);
    a2 += __uint_as_float(v.y << 16); a3 += __uint_as_float(v.y & 0xffff0000u);
    a4 += __uint_as_float(v.z << 16); a5 += __uint_as_float(v.z & 0xffff0000u);
    a6 += __uint_as_float(v.w << 16); a7 += __uint_as_float(v.w & 0xffff0000u);
  }
  uint4 o;
  o.x = (unsigned)f2bf(a0) | ((unsigned)f2bf(a1) << 16);
  o.y = (unsigned)f2bf(a2) | ((unsigned)f2bf(a3) << 16);
  o.z = (unsigned)f2bf(a4) | ((unsigned)f2bf(a5) << 16);
  o.w = (unsigned)f2bf(a6) | ((unsigned)f2bf(a7) << 16);
  hb4[(long long)wid * 64 + lane] = o;
}

// =================== 256x256 8-phase bf16 GEMM (R8 champion + m201 waits) ===================
// C[M,N] = A[M,K] * B[N,K]^T + bias.  BK=64, 512 thr = 8 waves (2Mx4N),
// per-wave 128x64. LDS 128KB = 2 K-tile buffers. 8 phases / 2 K-tiles per iter;
// counted vmcnt(2) at P4/P8 only. seg-swizzle phys_seg = seg ^ (row&7),
// both-sides (pre-swizzled global src + swizzled ds_read) -> 0 conflicts.
// R13 deltas vs R8 (both zero-ledger-risk):
//  (1) MFMA_Q issues ks-outer: same-acc dependent pairs 8 issues apart
//      (was back-to-back: dependent chain every 2nd MFMA).
//  (2) m201 wait recipe: lgkmcnt(8) pre-barrier in 12-read phases (P1/P5),
//      then SBAR; lgkmcnt(0); sched_barrier(0) (rule 18) before the MFMAs.

#define SBAR  __builtin_amdgcn_s_barrier()
#define SCHB  __builtin_amdgcn_sched_barrier(0)
#define VMC(n) asm volatile("s_waitcnt vmcnt(" #n ")" ::: "memory")
#define LGKM(n) asm volatile("s_waitcnt lgkmcnt(" #n ")" ::: "memory")
#define PRIO1 __builtin_amdgcn_s_setprio(1)
#define PRIO0 __builtin_amdgcn_s_setprio(0)

#define READ_A(qm, bufc) \
  _Pragma("unroll") for (int m_ = 0; m_ < 4; ++m_) { \
    const char* p_ = (bufc) + aOff + (qm) * 8192 + m_ * 2048; \
    aF[m_][0] = *(const bf16x8*)(p_ + sg0); \
    aF[m_][1] = *(const bf16x8*)(p_ + sg1); \
  }

#define READ_B(qn, bufc, DST) \
  _Pragma("unroll") for (int n_ = 0; n_ < 2; ++n_) { \
    const char* p_ = (bufc) + 32768 + bOff + (qn) * 4096 + n_ * 2048; \
    DST[n_][0] = *(const bf16x8*)(p_ + sg0); \
    DST[n_][1] = *(const bf16x8*)(p_ + sg1); \
  }

// ks-outer: all 8 ks0-MFMAs, then all 8 ks1-MFMAs (dependent pairs 8 apart)
#define MFMA_Q(qm, qn, BQ) \
  _Pragma("unroll") for (int ks_ = 0; ks_ < 2; ++ks_) \
    _Pragma("unroll") for (int m_ = 0; m_ < 4; ++m_) \
      _Pragma("unroll") for (int n_ = 0; n_ < 2; ++n_) \
        acc[(qm)*4+m_][(qn)*2+n_] = __builtin_amdgcn_mfma_f32_16x16x32_bf16( \
            aF[m_][ks_], BQ[n_][ks_], acc[(qm)*4+m_][(qn)*2+n_], 0, 0, 0);

#define STAGE_A(bufc, kt, ha) \
  _Pragma("unroll") for (int j_ = 0; j_ < 2; ++j_) { \
    int rl_ = (ha) * 128 + (w * 2 + j_) * 8 + stSub; \
    int gr_ = aRow0 + rl_; if (gr_ > Mm1) gr_ = Mm1; \
    __builtin_amdgcn_global_load_lds( \
      (const __attribute__((address_space(1))) void*)(A + (long long)gr_ * K + (kt) * 64 + stSeg8), \
      (__attribute__((address_space(3))) void*)((bufc) + (ha) * 16384 + (w * 2 + j_) * 1024), \
      16, 0, 0); \
  }

#define STAGE_B(bufc, kt, ha) \
  _Pragma("unroll") for (int j_ = 0; j_ < 2; ++j_) { \
    int rl_ = (ha) * 128 + (w * 2 + j_) * 8 + stSub; \
    int gr_ = bRow0 + rl_; \
    __builtin_amdgcn_global_load_lds( \
      (const __attribute__((address_space(1))) void*)(B + (long long)gr_ * K + (kt) * 64 + stSeg8), \
      (__attribute__((address_space(3))) void*)((bufc) + 32768 + (ha) * 16384 + (w * 2 + j_) * 1024), \
      16, 0, 0); \
  }

template<bool OUT_BF16>
__global__ __launch_bounds__(512, 2)
void k_gemm256(const unsigned short* __restrict__ A,   // [M,K] bf16
               const unsigned short* __restrict__ B,   // [N,K] bf16
               const float* __restrict__ bias,         // [N]
               void* __restrict__ C,                   // [M,N] f32 or bf16
               int M, int N, int K)
{
  __shared__ __align__(16) char lds[131072];   // 2 x (A 32KB + B 32KB)

  const int tid  = threadIdx.x;
  const int lane = tid & 63;
  const int w    = tid >> 6;       // 0..7
  const int wr   = w >> 2;         // 0..1  (M)
  const int wc   = w & 3;          // 0..3  (N)

  // grid mapping: bn-chunk per XCD if possible, else m204 bijective swizzle
  const int nwg  = gridDim.x * gridDim.y;
  const int orig = blockIdx.y * gridDim.x + blockIdx.x;
  int bn, bm;
  if ((gridDim.x & 7) == 0 && (nwg & 7) == 0) {
    const int xcd = orig & 7;
    const int j   = orig >> 3;
    const int chunk = gridDim.x >> 3;
    bn = xcd * chunk + (j % chunk);
    bm = j / chunk;
  } else {
    const int q = nwg >> 3, r = nwg & 7;
    const int xcd = orig & 7, land = orig >> 3;
    const int nid = (xcd < r ? xcd * (q + 1) : r * (q + 1) + (xcd - r) * q) + land;
    bn = nid % gridDim.x;
    bm = nid / gridDim.x;
  }

  // per-lane constants
  const int lm = lane & 15;
  const int lk = lane >> 4;                       // 0..3
  const int l7 = lane & 7;
  const int sg0 = ((lk    ) ^ l7) * 16;           // swizzled seg byte off, ks=0
  const int sg1 = ((lk + 4) ^ l7) * 16;           // ks=1
  const int aOff = (wr * 128 + lm) * 128;         // A read base (bytes)
  const int bOff = (wc * 64  + lm) * 128;         // B read base (bytes)
  const int stSub  = lane >> 3;                   // 0..7
  const int stSeg8 = ((lane & 7) ^ stSub) * 8;    // pre-swizzled source seg (elems)
  const int aRow0 = bm * 256;
  const int bRow0 = bn * 256;
  const int Mm1 = M - 1;

  char* lb0 = (char*)lds;            // even K-tiles
  char* lb1 = (char*)lds + 65536;    // odd K-tiles

  f32x4 acc[8][4] = {};
  bf16x8 aF[4][2], bF0[2][2], bF1[2][2];

  const int nkt = K >> 6;            // 64-wide K tiles (even count for 512/4352)
  const int nit = nkt >> 1;

  // prologue: tile0 full + tile1.A0
  STAGE_A(lb0, 0, 0); STAGE_A(lb0, 0, 1); STAGE_B(lb0, 0, 0); STAGE_B(lb0, 0, 1);
  STAGE_A(lb1, 1, 0);
  VMC(2);
  SBAR;

  for (int i = 0; i < nit; ++i) {
    const int ktO = 2 * i + 1;
    int ktE2 = 2 * i + 2; if (ktE2 >= nkt) ktE2 = nkt - 1;  // clamped junk on last iter
    int ktO2 = 2 * i + 3; if (ktO2 >= nkt) ktO2 = nkt - 1;
    // P1: tile E quad(0,0)  [12 reads -> lgkm(8) smoothing]
    READ_A(0, lb0); READ_B(0, lb0, bF0);
    STAGE_A(lb1, ktO, 1);
    LGKM(8); SBAR; LGKM(0); SCHB; PRIO1; MFMA_Q(0, 0, bF0); PRIO0; SCHB; SBAR;
    // P2: quad(0,1)
    READ_B(1, lb0, bF1);
    STAGE_B(lb1, ktO, 0);
    SBAR; LGKM(0); SCHB; PRIO1; MFMA_Q(0, 1, bF1); PRIO0; SCHB; SBAR;
    // P3: quad(1,1)
    READ_A(1, lb0);
    STAGE_B(lb1, ktO, 1);
    SBAR; LGKM(0); SCHB; PRIO1; MFMA_Q(1, 1, bF1); PRIO0; SCHB; SBAR;
    // P4: quad(1,0)  (no new reads); VMC(2) completes tile O staging
    STAGE_A(lb0, ktE2, 0);
    SBAR; PRIO1; MFMA_Q(1, 0, bF0); PRIO0; SCHB; VMC(2); SBAR;
    // P5: tile O quad(0,0)  [12 reads -> lgkm(8) smoothing]
    READ_A(0, lb1); READ_B(0, lb1, bF0);
    STAGE_A(lb0, ktE2, 1);
    LGKM(8); SBAR; LGKM(0); SCHB; PRIO1; MFMA_Q(0, 0, bF0); PRIO0; SCHB; SBAR;
    // P6: quad(0,1)
    READ_B(1, lb1, bF1);
    STAGE_B(lb0, ktE2, 0);
    SBAR; LGKM(0); SCHB; PRIO1; MFMA_Q(0, 1, bF1); PRIO0; SCHB; SBAR;
    // P7: quad(1,1)
    READ_A(1, lb1);
    STAGE_B(lb0, ktE2, 1);
    SBAR; LGKM(0); SCHB; PRIO1; MFMA_Q(1, 1, bF1); PRIO0; SCHB; SBAR;
    // P8: quad(1,0); VMC(2) completes tile E' staging
    STAGE_A(lb1, ktO2, 0);
    SBAR; PRIO1; MFMA_Q(1, 0, bF0); PRIO0; SCHB; VMC(2); SBAR;
  }

  // epilogue: C[row, col] = acc + bias
#pragma unroll
  for (int in = 0; in < 4; ++in) {
    const int col = bn * 256 + wc * 64 + in * 16 + lm;
    const float bv = bias[col];
#pragma unroll
    for (int im = 0; im < 8; ++im) {
      const int row0 = bm * 256 + wr * 128 + im * 16 + lk * 4;
#pragma unroll
      for (int jj = 0; jj < 4; ++jj) {
        const int row = row0 + jj;
        if (row < M) {
          const float v = acc[im][in][jj] + bv;
          if (OUT_BF16)
            __builtin_nontemporal_store(f2bf(v), &((unsigned short*)C)[(long long)row * N + col]);
          else
            __builtin_nontemporal_store(v, &((float*)C)[(long long)row * N + col]);
        }
      }
    }
  }
}

extern "C" void kernel_launch(void* const* d_in, const int* in_sizes, int n_in,
                              void* d_out, int out_size, void* d_ws, size_t ws_size,
                              hipStream_t stream) {
  const float* x  = (const float*)d_in[0];
  const int*   ei = (const int*)d_in[1];      // int32 or int64 — detected on device
  const float* W1 = (const float*)d_in[2];
  const float* b1 = (const float*)d_in[3];
  const float* W2 = (const float*)d_in[4];
  const float* b2 = (const float*)d_in[5];
  float* out = (float*)d_out;
  char* ws = (char*)d_ws;

  // workspace layout (bytes, 16B-aligned)
  int* flag            = (int*)(ws + 0);                    // 256
  int* deg             = (int*)(ws + 256);                  // 80,000
  int* offs            = (int*)(ws + 80256);                // 80,000
  int* cursor          = (int*)(ws + 160256);               // 80,000
  int* csr             = (int*)(ws + 240256);               // 2,560,000
  unsigned short* xb   = (unsigned short*)(ws + 2800256);   // 20,480,000
  unsigned short* hb   = (unsigned short*)(ws + 23280256);  // 20,480,000
  unsigned short* w1b  = (unsigned short*)(ws + 43760256);  //  4,456,448
  unsigned short* w2b  = (unsigned short*)(ws + 48216704);  // 71,303,168
  const size_t h1_off  = 119519872;
  if (ws_size < h1_off + (size_t)256 * MID * 2) return;
  unsigned short* h1b  = (unsigned short*)(ws + h1_off);

  long long rem = (long long)ws_size - (long long)h1_off;
  int max_rows = (int)(rem / ((long long)MID * 2));
  max_rows = (max_rows / 256) * 256;
  if (max_rows > 20224) max_rows = 20224;

  // 0) detect edge_index width
  k_detect64<<<1, 256, 0, stream>>>(ei, flag);

  // 1) CSR build
  k_zero_i32<<<(NN + 255) / 256, 256, 0, stream>>>(deg, NN);
  k_count<<<(NE + 255) / 256, 256, 0, stream>>>(ei, flag, deg);
  k_scan<<<1, 1024, 0, stream>>>(deg, offs, cursor);
  k_fill<<<(NE + 255) / 256, 256, 0, stream>>>(ei, flag, cursor, csr);

  // 2) conversions to bf16 (x first: gather depends on it)
  k_f32_to_bf16<<<2048, 256, 0, stream>>>((const float4*)x,  (uint2*)xb,  NN * HID / 4);
  k_f32_to_bf16<<<1024, 256, 0, stream>>>((const float4*)W1, (uint2*)w1b, MID * HID / 4);
  k_f32_to_bf16<<<2048, 256, 0, stream>>>((const float4*)W2, (uint2*)w2b, VOC * MID / 4);

  // 3) fused gather: hb = bf16(x_i + sum_j bf16(x_j))
  k_gather2<<<(NN + 3) / 4, 256, 0, stream>>>((const float4*)x, (const uint4*)xb,
                                              offs, deg, csr, (uint4*)hb);

  // 4+5) chunked GEMM1 -> GEMM2 over M (usually a single chunk)
  for (int r0 = 0; r0 < NN; r0 += max_rows) {
    int mrows = (NN - r0 < max_rows) ? (NN - r0) : max_rows;
    dim3 g1(MID / 256, (mrows + 255) / 256);
    k_gemm256<true><<<g1, 512, 0, stream>>>(hb + (size_t)r0 * HID, w1b, b1,
                                            (void*)h1b, mrows, MID, HID);
    dim3 g2(VOC / 256, (mrows + 255) / 256);
    k_gemm256<false><<<g2, 512, 0, stream>>>(h1b, w2b, b2,
                                             (void*)(out + (size_t)r0 * VOC), mrows, VOC, MID);
  }
}

// Round 14
// 670.616 us; speedup vs baseline: 2.9430x; 2.6649x over previous
//
#include <hip/hip_runtime.h>
#include <hip/hip_bf16.h>
#include <stdint.h>

// Problem constants
#define NN 20000      // nodes
#define NE 640000     // edges
#define HID 512
#define MID 4352
#define VOC 8192

typedef __attribute__((ext_vector_type(4))) float f32x4;
typedef __attribute__((ext_vector_type(8))) short bf16x8;

__device__ __forceinline__ unsigned short f2bf(float f) {
  unsigned int u = __float_as_uint(f);
  u += 0x7fffu + ((u >> 16) & 1u);   // round-to-nearest-even
  return (unsigned short)(u >> 16);
}

// ---------------- detect edge_index storage width ----------------
__global__ void k_detect64(const int* __restrict__ ei32, int* __restrict__ flag) {
  __shared__ int any_nz;
  if (threadIdx.x == 0) any_nz = 0;
  __syncthreads();
  int v = ei32[2 * threadIdx.x + 1];
  if (v != 0) atomicOr(&any_nz, 1);
  __syncthreads();
  if (threadIdx.x == 0) *flag = (any_nz == 0) ? 1 : 0;  // 1 => int64 layout
}

__global__ void k_zero_i32(int* __restrict__ p, int n) {
  int i = blockIdx.x * blockDim.x + threadIdx.x;
  if (i < n) p[i] = 0;
}

__global__ void k_count(const int* __restrict__ ei, const int* __restrict__ flag,
                        int* __restrict__ deg) {
  int e = blockIdx.x * blockDim.x + threadIdx.x;
  if (e >= NE) return;
  int is64 = *flag;
  int d = is64 ? ei[2 * (NE + e)] : ei[NE + e];
  if ((unsigned)d >= NN) return;
  atomicAdd(&deg[d], 1);
}

__global__ __launch_bounds__(1024)
void k_scan(const int* __restrict__ deg, int* __restrict__ offs, int* __restrict__ cursor) {
  __shared__ int part[1024];
  const int t = threadIdx.x;
  const int CH = (NN + 1023) / 1024;  // 20
  const int base = t * CH;
  int s = 0;
  for (int i = 0; i < CH; ++i) { int idx = base + i; if (idx < NN) s += deg[idx]; }
  part[t] = s;
  __syncthreads();
  for (int off = 1; off < 1024; off <<= 1) {
    int v = (t >= off) ? part[t - off] : 0;
    __syncthreads();
    part[t] += v;
    __syncthreads();
  }
  int run = (t == 0) ? 0 : part[t - 1];  // exclusive prefix
  for (int i = 0; i < CH; ++i) {
    int idx = base + i;
    if (idx < NN) { offs[idx] = run; cursor[idx] = run; run += deg[idx]; }
  }
}

__global__ void k_fill(const int* __restrict__ ei, const int* __restrict__ flag,
                       int* __restrict__ cursor, int* __restrict__ csr) {
  int e = blockIdx.x * blockDim.x + threadIdx.x;
  if (e >= NE) return;
  int is64 = *flag;
  int s, d;
  if (is64) { s = ei[2 * e]; d = ei[2 * (NE + e)]; }
  else      { s = ei[e];     d = ei[NE + e]; }
  if ((unsigned)s >= NN || (unsigned)d >= NN) return;
  int pos = atomicAdd(&cursor[d], 1);
  csr[pos] = s;
}

__global__ void k_f32_to_bf16(const float4* __restrict__ src, uint2* __restrict__ dst, int n4) {
  int i = blockIdx.x * blockDim.x + threadIdx.x;
  int stride = gridDim.x * blockDim.x;
  for (; i < n4; i += stride) {
    float4 v = src[i];
    uint2 o;
    o.x = (unsigned)f2bf(v.x) | ((unsigned)f2bf(v.y) << 16);
    o.y = (unsigned)f2bf(v.z) | ((unsigned)f2bf(v.w) << 16);
    dst[i] = o;
  }
}

// ---------------- fused gather: hb = bf16(x_i + sum bf16(x_j)) ----------------
__global__ __launch_bounds__(256)
void k_gather2(const float4* __restrict__ x4, const uint4* __restrict__ xb4,
               const int* __restrict__ offs, const int* __restrict__ deg,
               const int* __restrict__ csr, uint4* __restrict__ hb4) {
  const int wid = blockIdx.x * (blockDim.x >> 6) + (threadIdx.x >> 6);
  if (wid >= NN) return;
  const int lane = threadIdx.x & 63;
  float4 s0 = x4[(long long)wid * 128 + lane * 2];
  float4 s1 = x4[(long long)wid * 128 + lane * 2 + 1];
  float a0 = s0.x, a1 = s0.y, a2 = s0.z, a3 = s0.w;
  float a4 = s1.x, a5 = s1.y, a6 = s1.z, a7 = s1.w;
  const int beg = offs[wid];
  const int dc  = deg[wid];
  for (int j = 0; j < dc; ++j) {
    int s = csr[beg + j];
    uint4 v = xb4[(long long)s * 64 + lane];
    a0 += __uint_as_float(v.x << 16); a1 += __uint_as_float(v.x & 0xffff0000u);
    a2 += __uint_as_float(v.y << 16); a3 += __uint_as_float(v.y & 0xffff0000u);
    a4 += __uint_as_float(v.z << 16); a5 += __uint_as_float(v.z & 0xffff0000u);
    a6 += __uint_as_float(v.w << 16); a7 += __uint_as_float(v.w & 0xffff0000u);
  }
  uint4 o;
  o.x = (unsigned)f2bf(a0) | ((unsigned)f2bf(a1) << 16);
  o.y = (unsigned)f2bf(a2) | ((unsigned)f2bf(a3) << 16);
  o.z = (unsigned)f2bf(a4) | ((unsigned)f2bf(a5) << 16);
  o.w = (unsigned)f2bf(a6) | ((unsigned)f2bf(a7) << 16);
  hb4[(long long)wid * 64 + lane] = o;
}

// ---------------- W1 [MID,HID] f32 -> w1t [HID,MID] bf16 (LDS-tiled transpose) ----------------
__global__ __launch_bounds__(256)
void k_transpose_cvt(const float* __restrict__ W1, unsigned short* __restrict__ w1t) {
  __shared__ float tile[64][65];
  const int hb0 = blockIdx.x * 64;   // HID block
  const int mb0 = blockIdx.y * 64;   // MID block
  for (int i = threadIdx.x; i < 4096; i += 256) {
    int r = i >> 6, c = i & 63;
    tile[r][c] = W1[(long long)(mb0 + r) * HID + hb0 + c];
  }
  __syncthreads();
  for (int i = threadIdx.x; i < 4096; i += 256) {
    int r = i >> 6, c = i & 63;
    w1t[(long long)(hb0 + r) * MID + mb0 + c] = f2bf(tile[c][r]);
  }
}

// ---------------- b2' = W2 @ b1 + b2 (one wave per output row) ----------------
__global__ __launch_bounds__(256)
void k_bias2(const unsigned short* __restrict__ w2b, const float* __restrict__ b1,
             const float* __restrict__ b2, float* __restrict__ b2p) {
  const int v = blockIdx.x * 4 + (threadIdx.x >> 6);
  if (v >= VOC) return;
  const int lane = threadIdx.x & 63;
  float s = 0.f;
  for (int m = lane; m < MID; m += 64) {
    float wv = __uint_as_float(((unsigned)w2b[(long long)v * MID + m]) << 16);
    s += wv * b1[m];
  }
#pragma unroll
  for (int off = 32; off; off >>= 1) s += __shfl_down(s, off);
  if (lane == 0) b2p[v] = s + b2[v];
}

// ---------------- combine K-split partials: wcb = bf16(p0 + p1) ----------------
__global__ void k_combine(const float4* __restrict__ a, const float4* __restrict__ b,
                          uint2* __restrict__ dst, int n4) {
  int i = blockIdx.x * blockDim.x + threadIdx.x;
  int stride = gridDim.x * blockDim.x;
  for (; i < n4; i += stride) {
    float4 u = a[i], v = b[i];
    uint2 o;
    o.x = (unsigned)f2bf(u.x + v.x) | ((unsigned)f2bf(u.y + v.y) << 16);
    o.y = (unsigned)f2bf(u.z + v.z) | ((unsigned)f2bf(u.w + v.w) << 16);
    dst[i] = o;
  }
}

// =================== 256x256 8-phase bf16 GEMM (R13 champion + lda/ldb + z K-split) ===================
// C[M,N] = A[M,K]*B[N,K]^T + bias. BK=64, 512 thr = 8 waves (2Mx4N), per-wave 128x64.
// blockIdx.z splits K into gridDim.z contiguous ranges (each an even # of K-tiles);
// partial z writes to C + z*M*N (caller combines). lda/ldb = row strides of A/B.

#define SBAR  __builtin_amdgcn_s_barrier()
#define SCHB  __builtin_amdgcn_sched_barrier(0)
#define VMC(n) asm volatile("s_waitcnt vmcnt(" #n ")" ::: "memory")
#define LGKM(n) asm volatile("s_waitcnt lgkmcnt(" #n ")" ::: "memory")
#define PRIO1 __builtin_amdgcn_s_setprio(1)
#define PRIO0 __builtin_amdgcn_s_setprio(0)

#define READ_A(qm, bufc) \
  _Pragma("unroll") for (int m_ = 0; m_ < 4; ++m_) { \
    const char* p_ = (bufc) + aOff + (qm) * 8192 + m_ * 2048; \
    aF[m_][0] = *(const bf16x8*)(p_ + sg0); \
    aF[m_][1] = *(const bf16x8*)(p_ + sg1); \
  }

#define READ_B(qn, bufc, DST) \
  _Pragma("unroll") for (int n_ = 0; n_ < 2; ++n_) { \
    const char* p_ = (bufc) + 32768 + bOff + (qn) * 4096 + n_ * 2048; \
    DST[n_][0] = *(const bf16x8*)(p_ + sg0); \
    DST[n_][1] = *(const bf16x8*)(p_ + sg1); \
  }

#define MFMA_Q(qm, qn, BQ) \
  _Pragma("unroll") for (int ks_ = 0; ks_ < 2; ++ks_) \
    _Pragma("unroll") for (int m_ = 0; m_ < 4; ++m_) \
      _Pragma("unroll") for (int n_ = 0; n_ < 2; ++n_) \
        acc[(qm)*4+m_][(qn)*2+n_] = __builtin_amdgcn_mfma_f32_16x16x32_bf16( \
            aF[m_][ks_], BQ[n_][ks_], acc[(qm)*4+m_][(qn)*2+n_], 0, 0, 0);

#define STAGE_A(bufc, kt, ha) \
  _Pragma("unroll") for (int j_ = 0; j_ < 2; ++j_) { \
    int rl_ = (ha) * 128 + (w * 2 + j_) * 8 + stSub; \
    int gr_ = aRow0 + rl_; if (gr_ > Mm1) gr_ = Mm1; \
    __builtin_amdgcn_global_load_lds( \
      (const __attribute__((address_space(1))) void*)(Ap + (long long)gr_ * lda + (kt) * 64 + stSeg8), \
      (__attribute__((address_space(3))) void*)((bufc) + (ha) * 16384 + (w * 2 + j_) * 1024), \
      16, 0, 0); \
  }

#define STAGE_B(bufc, kt, ha) \
  _Pragma("unroll") for (int j_ = 0; j_ < 2; ++j_) { \
    int rl_ = (ha) * 128 + (w * 2 + j_) * 8 + stSub; \
    int gr_ = bRow0 + rl_; \
    __builtin_amdgcn_global_load_lds( \
      (const __attribute__((address_space(1))) void*)(Bp + (long long)gr_ * ldb + (kt) * 64 + stSeg8), \
      (__attribute__((address_space(3))) void*)((bufc) + 32768 + (ha) * 16384 + (w * 2 + j_) * 1024), \
      16, 0, 0); \
  }

template<bool OUT_BF16>
__global__ __launch_bounds__(512, 2)
void k_gemm256(const unsigned short* __restrict__ A,   // [M,K] bf16 (stride lda)
               const unsigned short* __restrict__ B,   // [N,K] bf16 (stride ldb)
               const float* __restrict__ bias,         // [N]
               void* __restrict__ C,                   // [M,N] f32 or bf16 (+ z*M*N)
               int M, int N, int K, int lda, int ldb)
{
  __shared__ __align__(16) char lds[131072];   // 2 x (A 32KB + B 32KB)

  const int tid  = threadIdx.x;
  const int lane = tid & 63;
  const int w    = tid >> 6;       // 0..7
  const int wr   = w >> 2;         // 0..1  (M)
  const int wc   = w & 3;          // 0..3  (N)

  // K-split
  const int z  = blockIdx.z;
  const int Kl = K / gridDim.z;                       // even # of 64-tiles per z
  const unsigned short* Ap = A + (long long)z * Kl;
  const unsigned short* Bp = B + (long long)z * Kl;
  char* Cz = (char*)C + (long long)z * M * N * (OUT_BF16 ? 2 : 4);

  // grid mapping: bn-chunk per XCD if possible, else m204 bijective swizzle
  const int nwg  = gridDim.x * gridDim.y;
  const int orig = blockIdx.y * gridDim.x + blockIdx.x;
  int bn, bm;
  if ((gridDim.x & 7) == 0 && (nwg & 7) == 0) {
    const int xcd = orig & 7;
    const int j   = orig >> 3;
    const int chunk = gridDim.x >> 3;
    bn = xcd * chunk + (j % chunk);
    bm = j / chunk;
  } else {
    const int q = nwg >> 3, r = nwg & 7;
    const int xcd = orig & 7, land = orig >> 3;
    const int nid = (xcd < r ? xcd * (q + 1) : r * (q + 1) + (xcd - r) * q) + land;
    bn = nid % gridDim.x;
    bm = nid / gridDim.x;
  }

  // per-lane constants
  const int lm = lane & 15;
  const int lk = lane >> 4;                       // 0..3
  const int l7 = lane & 7;
  const int sg0 = ((lk    ) ^ l7) * 16;           // swizzled seg byte off, ks=0
  const int sg1 = ((lk + 4) ^ l7) * 16;           // ks=1
  const int aOff = (wr * 128 + lm) * 128;         // A read base (bytes)
  const int bOff = (wc * 64  + lm) * 128;         // B read base (bytes)
  const int stSub  = lane >> 3;                   // 0..7
  const int stSeg8 = ((lane & 7) ^ stSub) * 8;    // pre-swizzled source seg (elems)
  const int aRow0 = bm * 256;
  const int bRow0 = bn * 256;
  const int Mm1 = M - 1;

  char* lb0 = (char*)lds;            // even K-tiles
  char* lb1 = (char*)lds + 65536;    // odd K-tiles

  f32x4 acc[8][4] = {};
  bf16x8 aF[4][2], bF0[2][2], bF1[2][2];

  const int nkt = Kl >> 6;           // 64-wide K tiles (even by construction)
  const int nit = nkt >> 1;

  // prologue: tile0 full + tile1.A0
  STAGE_A(lb0, 0, 0); STAGE_A(lb0, 0, 1); STAGE_B(lb0, 0, 0); STAGE_B(lb0, 0, 1);
  STAGE_A(lb1, 1, 0);
  VMC(2);
  SBAR;

  for (int i = 0; i < nit; ++i) {
    const int ktO = 2 * i + 1;
    int ktE2 = 2 * i + 2; if (ktE2 >= nkt) ktE2 = nkt - 1;  // clamped junk on last iter
    int ktO2 = 2 * i + 3; if (ktO2 >= nkt) ktO2 = nkt - 1;
    // P1: tile E quad(0,0)  [12 reads -> lgkm(8) smoothing]
    READ_A(0, lb0); READ_B(0, lb0, bF0);
    STAGE_A(lb1, ktO, 1);
    LGKM(8); SBAR; LGKM(0); SCHB; PRIO1; MFMA_Q(0, 0, bF0); PRIO0; SCHB; SBAR;
    // P2: quad(0,1)
    READ_B(1, lb0, bF1);
    STAGE_B(lb1, ktO, 0);
    SBAR; LGKM(0); SCHB; PRIO1; MFMA_Q(0, 1, bF1); PRIO0; SCHB; SBAR;
    // P3: quad(1,1)
    READ_A(1, lb0);
    STAGE_B(lb1, ktO, 1);
    SBAR; LGKM(0); SCHB; PRIO1; MFMA_Q(1, 1, bF1); PRIO0; SCHB; SBAR;
    // P4: quad(1,0); VMC(2) completes tile O staging
    STAGE_A(lb0, ktE2, 0);
    SBAR; PRIO1; MFMA_Q(1, 0, bF0); PRIO0; SCHB; VMC(2); SBAR;
    // P5: tile O quad(0,0)
    READ_A(0, lb1); READ_B(0, lb1, bF0);
    STAGE_A(lb0, ktE2, 1);
    LGKM(8); SBAR; LGKM(0); SCHB; PRIO1; MFMA_Q(0, 0, bF0); PRIO0; SCHB; SBAR;
    // P6: quad(0,1)
    READ_B(1, lb1, bF1);
    STAGE_B(lb0, ktE2, 0);
    SBAR; LGKM(0); SCHB; PRIO1; MFMA_Q(0, 1, bF1); PRIO0; SCHB; SBAR;
    // P7: quad(1,1)
    READ_A(1, lb1);
    STAGE_B(lb0, ktE2, 1);
    SBAR; LGKM(0); SCHB; PRIO1; MFMA_Q(1, 1, bF1); PRIO0; SCHB; SBAR;
    // P8: quad(1,0); VMC(2) completes tile E' staging
    STAGE_A(lb1, ktO2, 0);
    SBAR; PRIO1; MFMA_Q(1, 0, bF0); PRIO0; SCHB; VMC(2); SBAR;
  }

  // epilogue: C[row, col] = acc + bias
#pragma unroll
  for (int in = 0; in < 4; ++in) {
    const int col = bn * 256 + wc * 64 + in * 16 + lm;
    const float bv = bias[col];
#pragma unroll
    for (int im = 0; im < 8; ++im) {
      const int row0 = bm * 256 + wr * 128 + im * 16 + lk * 4;
#pragma unroll
      for (int jj = 0; jj < 4; ++jj) {
        const int row = row0 + jj;
        if (row < M) {
          const float v = acc[im][in][jj] + bv;
          if (OUT_BF16)
            __builtin_nontemporal_store(f2bf(v), &((unsigned short*)Cz)[(long long)row * N + col]);
          else
            __builtin_nontemporal_store(v, &((float*)Cz)[(long long)row * N + col]);
        }
      }
    }
  }
}

extern "C" void kernel_launch(void* const* d_in, const int* in_sizes, int n_in,
                              void* d_out, int out_size, void* d_ws, size_t ws_size,
                              hipStream_t stream) {
  const float* x  = (const float*)d_in[0];
  const int*   ei = (const int*)d_in[1];      // int32 or int64 — detected on device
  const float* W1 = (const float*)d_in[2];
  const float* b1 = (const float*)d_in[3];
  const float* W2 = (const float*)d_in[4];
  const float* b2 = (const float*)d_in[5];
  float* out = (float*)d_out;
  char* ws = (char*)d_ws;

  // workspace layout (bytes, 16B-aligned)
  int* flag            = (int*)(ws + 0);                     // 256
  int* deg             = (int*)(ws + 256);                   // 80,000
  int* offs            = (int*)(ws + 80256);                 // 80,000
  int* cursor          = (int*)(ws + 160256);                // 80,000
  int* csr             = (int*)(ws + 240256);                // 2,560,000
  unsigned short* xb   = (unsigned short*)(ws + 2800256);    // 20,480,000
  unsigned short* hb   = (unsigned short*)(ws + 23280256);   // 20,480,000
  unsigned short* w1t  = (unsigned short*)(ws + 43760256);   //  4,456,448  [HID x MID]
  unsigned short* w2b  = (unsigned short*)(ws + 48216704);   // 71,303,168
  float*          wcp  = (float*)(ws + 119519872);           // 2 x 16,777,216 (K-split partials)
  unsigned short* wcb  = (unsigned short*)(ws + 153074304);  //  8,388,608  [VOC x HID]
  float*          b2p  = (float*)(ws + 161462912);           //     32,768
  float*          zb   = (float*)(ws + 161495680);           //      2,048  (zero bias)
  if (ws_size < 161497728ULL) return;

  // 0) detect edge_index width
  k_detect64<<<1, 256, 0, stream>>>(ei, flag);

  // 1) CSR build (+ zero the zero-bias)
  k_zero_i32<<<(NN + 255) / 256, 256, 0, stream>>>(deg, NN);
  k_zero_i32<<<2, 256, 0, stream>>>((int*)zb, 512);
  k_count<<<(NE + 255) / 256, 256, 0, stream>>>(ei, flag, deg);
  k_scan<<<1, 1024, 0, stream>>>(deg, offs, cursor);
  k_fill<<<(NE + 255) / 256, 256, 0, stream>>>(ei, flag, cursor, csr);

  // 2) conversions: x -> xb (gather needs it), W2 -> w2b, W1 -> w1t (transposed)
  k_f32_to_bf16<<<2048, 256, 0, stream>>>((const float4*)x,  (uint2*)xb,  NN * HID / 4);
  k_f32_to_bf16<<<2048, 256, 0, stream>>>((const float4*)W2, (uint2*)w2b, VOC * MID / 4);
  {
    dim3 gt(HID / 64, MID / 64);   // (8, 68)
    k_transpose_cvt<<<gt, 256, 0, stream>>>(W1, w1t);
  }

  // 3) fused gather: hb = bf16(x_i + sum_j bf16(x_j))
  k_gather2<<<(NN + 3) / 4, 256, 0, stream>>>((const float4*)x, (const uint4*)xb,
                                              offs, deg, csr, (uint4*)hb);

  // 4) b2' = W2 @ b1 + b2
  k_bias2<<<VOC / 4, 256, 0, stream>>>(w2b, b1, b2, b2p);

  // 5) Wc = W2 @ W1 : [VOC, HID], K=MID split in 2 (f32 partials), then combine->bf16
  {
    dim3 g(HID / 256, VOC / 256, 2);   // (2, 32, 2) = 128 blocks
    k_gemm256<false><<<g, 512, 0, stream>>>(w2b, w1t, zb, (void*)wcp,
                                            VOC, HID, MID, MID, MID);
    k_combine<<<1024, 256, 0, stream>>>((const float4*)wcp,
                                        (const float4*)(wcp + (size_t)VOC * HID),
                                        (uint2*)wcb, VOC * HID / 4);
  }

  // 6) out = hb @ Wc^T + b2' : [NN, VOC], K=HID
  {
    dim3 g(VOC / 256, (NN + 255) / 256, 1);   // (32, 79)
    k_gemm256<false><<<g, 512, 0, stream>>>(hb, wcb, b2p, (void*)out,
                                            NN, VOC, HID, HID, HID);
  }
}

// Round 15
// 632.125 us; speedup vs baseline: 3.1222x; 1.0609x over previous
//
#include <hip/hip_runtime.h>
#include <hip/hip_bf16.h>
#include <stdint.h>

// Problem constants
#define NN 20000      // nodes
#define NE 640000     // edges
#define HID 512
#define MID 4352
#define VOC 8192

typedef __attribute__((ext_vector_type(4))) float f32x4;
typedef __attribute__((ext_vector_type(8))) short bf16x8;

__device__ __forceinline__ unsigned short f2bf(float f) {
  unsigned int u = __float_as_uint(f);
  u += 0x7fffu + ((u >> 16) & 1u);   // round-to-nearest-even
  return (unsigned short)(u >> 16);
}

// ---------------- detect edge_index storage width ----------------
__global__ void k_detect64(const int* __restrict__ ei32, int* __restrict__ flag) {
  __shared__ int any_nz;
  if (threadIdx.x == 0) any_nz = 0;
  __syncthreads();
  int v = ei32[2 * threadIdx.x + 1];
  if (v != 0) atomicOr(&any_nz, 1);
  __syncthreads();
  if (threadIdx.x == 0) *flag = (any_nz == 0) ? 1 : 0;  // 1 => int64 layout
}

__global__ void k_zero_i32(int* __restrict__ p, int n) {
  int i = blockIdx.x * blockDim.x + threadIdx.x;
  if (i < n) p[i] = 0;
}

__global__ void k_count(const int* __restrict__ ei, const int* __restrict__ flag,
                        int* __restrict__ deg) {
  int e = blockIdx.x * blockDim.x + threadIdx.x;
  if (e >= NE) return;
  int is64 = *flag;
  int d = is64 ? ei[2 * (NE + e)] : ei[NE + e];
  if ((unsigned)d >= NN) return;
  atomicAdd(&deg[d], 1);
}

__global__ __launch_bounds__(1024)
void k_scan(const int* __restrict__ deg, int* __restrict__ offs, int* __restrict__ cursor) {
  __shared__ int part[1024];
  const int t = threadIdx.x;
  const int CH = (NN + 1023) / 1024;  // 20
  const int base = t * CH;
  int s = 0;
  for (int i = 0; i < CH; ++i) { int idx = base + i; if (idx < NN) s += deg[idx]; }
  part[t] = s;
  __syncthreads();
  for (int off = 1; off < 1024; off <<= 1) {
    int v = (t >= off) ? part[t - off] : 0;
    __syncthreads();
    part[t] += v;
    __syncthreads();
  }
  int run = (t == 0) ? 0 : part[t - 1];  // exclusive prefix
  for (int i = 0; i < CH; ++i) {
    int idx = base + i;
    if (idx < NN) { offs[idx] = run; cursor[idx] = run; run += deg[idx]; }
  }
}

__global__ void k_fill(const int* __restrict__ ei, const int* __restrict__ flag,
                       int* __restrict__ cursor, int* __restrict__ csr) {
  int e = blockIdx.x * blockDim.x + threadIdx.x;
  if (e >= NE) return;
  int is64 = *flag;
  int s, d;
  if (is64) { s = ei[2 * e]; d = ei[2 * (NE + e)]; }
  else      { s = ei[e];     d = ei[NE + e]; }
  if ((unsigned)s >= NN || (unsigned)d >= NN) return;
  int pos = atomicAdd(&cursor[d], 1);
  csr[pos] = s;
}

__global__ void k_f32_to_bf16(const float4* __restrict__ src, uint2* __restrict__ dst, int n4) {
  int i = blockIdx.x * blockDim.x + threadIdx.x;
  int stride = gridDim.x * blockDim.x;
  for (; i < n4; i += stride) {
    float4 v = src[i];
    uint2 o;
    o.x = (unsigned)f2bf(v.x) | ((unsigned)f2bf(v.y) << 16);
    o.y = (unsigned)f2bf(v.z) | ((unsigned)f2bf(v.w) << 16);
    dst[i] = o;
  }
}

// ---------------- fused gather: hb = bf16(x_i + sum bf16(x_j)) ----------------
__global__ __launch_bounds__(256)
void k_gather2(const float4* __restrict__ x4, const uint4* __restrict__ xb4,
               const int* __restrict__ offs, const int* __restrict__ deg,
               const int* __restrict__ csr, uint4* __restrict__ hb4) {
  const int wid = blockIdx.x * (blockDim.x >> 6) + (threadIdx.x >> 6);
  if (wid >= NN) return;
  const int lane = threadIdx.x & 63;
  float4 s0 = x4[(long long)wid * 128 + lane * 2];
  float4 s1 = x4[(long long)wid * 128 + lane * 2 + 1];
  float a0 = s0.x, a1 = s0.y, a2 = s0.z, a3 = s0.w;
  float a4 = s1.x, a5 = s1.y, a6 = s1.z, a7 = s1.w;
  const int beg = offs[wid];
  const int dc  = deg[wid];
  for (int j = 0; j < dc; ++j) {
    int s = csr[beg + j];
    uint4 v = xb4[(long long)s * 64 + lane];
    a0 += __uint_as_float(v.x << 16); a1 += __uint_as_float(v.x & 0xffff0000u);
    a2 += __uint_as_float(v.y << 16); a3 += __uint_as_float(v.y & 0xffff0000u);
    a4 += __uint_as_float(v.z << 16); a5 += __uint_as_float(v.z & 0xffff0000u);
    a6 += __uint_as_float(v.w << 16); a7 += __uint_as_float(v.w & 0xffff0000u);
  }
  uint4 o;
  o.x = (unsigned)f2bf(a0) | ((unsigned)f2bf(a1) << 16);
  o.y = (unsigned)f2bf(a2) | ((unsigned)f2bf(a3) << 16);
  o.z = (unsigned)f2bf(a4) | ((unsigned)f2bf(a5) << 16);
  o.w = (unsigned)f2bf(a6) | ((unsigned)f2bf(a7) << 16);
  hb4[(long long)wid * 64 + lane] = o;
}

// ---------------- W1 [MID,HID] f32 -> w1t [HID,MID] bf16 (LDS-tiled transpose) ----------------
__global__ __launch_bounds__(256)
void k_transpose_cvt(const float* __restrict__ W1, unsigned short* __restrict__ w1t) {
  __shared__ float tile[64][65];
  const int hb0 = blockIdx.x * 64;   // HID block
  const int mb0 = blockIdx.y * 64;   // MID block
  for (int i = threadIdx.x; i < 4096; i += 256) {
    int r = i >> 6, c = i & 63;
    tile[r][c] = W1[(long long)(mb0 + r) * HID + hb0 + c];
  }
  __syncthreads();
  for (int i = threadIdx.x; i < 4096; i += 256) {
    int r = i >> 6, c = i & 63;
    w1t[(long long)(hb0 + r) * MID + mb0 + c] = f2bf(tile[c][r]);
  }
}

// ---------------- fused W2 cvt + b2' row-dot: w2b = bf16(W2); b2p = W2@b1 + b2 ----------------
// one block per VOC row
__global__ __launch_bounds__(256)
void k_w2_cvt_bias(const float4* __restrict__ W2_4, const float4* __restrict__ b1_4,
                   const float* __restrict__ b2, uint2* __restrict__ w2b_2,
                   float* __restrict__ b2p) {
  __shared__ float red[256];
  const int v = blockIdx.x;
  const int t = threadIdx.x;
  const long long rb = (long long)v * (MID / 4);
  float s = 0.f;
  for (int i = t; i < MID / 4; i += 256) {   // 1088 float4 per row
    float4 w = W2_4[rb + i];
    float4 b = b1_4[i];
    uint2 o;
    o.x = (unsigned)f2bf(w.x) | ((unsigned)f2bf(w.y) << 16);
    o.y = (unsigned)f2bf(w.z) | ((unsigned)f2bf(w.w) << 16);
    w2b_2[rb + i] = o;
    s += w.x * b.x + w.y * b.y + w.z * b.z + w.w * b.w;
  }
  red[t] = s;
  __syncthreads();
  for (int off = 128; off; off >>= 1) {
    if (t < off) red[t] += red[t + off];
    __syncthreads();
  }
  if (t == 0) b2p[v] = red[0] + b2[v];
}

// ---------------- combine 4 K-split partials: wcb = bf16(p0+p1+p2+p3) ----------------
__global__ void k_combine4(const float4* __restrict__ p, uint2* __restrict__ dst, int n4) {
  int i = blockIdx.x * blockDim.x + threadIdx.x;
  int stride = gridDim.x * blockDim.x;
  const int seg = VOC * HID / 4;
  for (; i < n4; i += stride) {
    float4 a = p[i], b = p[i + seg], c = p[i + 2 * seg], d = p[i + 3 * seg];
    uint2 o;
    o.x = (unsigned)f2bf(a.x + b.x + c.x + d.x) | ((unsigned)f2bf(a.y + b.y + c.y + d.y) << 16);
    o.y = (unsigned)f2bf(a.z + b.z + c.z + d.z) | ((unsigned)f2bf(a.w + b.w + c.w + d.w) << 16);
    dst[i] = o;
  }
}

// =================== 256x256 8-phase bf16 GEMM (R13 schedule + lda/ldb + z-split + odd-tail) ===================
// C[M,N] = A[M,K]*B[N,K]^T + bias. BK=64, 512 thr = 8 waves (2Mx4N), per-wave 128x64.
// blockIdx.z splits K into gridDim.z contiguous ranges (any # of 64-tiles >= 2;
// odd counts handled by a barrier-free tail on the last even-indexed tile, which
// is fully staged+drained by the final loop iteration's P4/P5 + P8 VMC(2)).
// Partial z writes to C + z*M*N (caller combines). lda/ldb = row strides.

#define SBAR  __builtin_amdgcn_s_barrier()
#define SCHB  __builtin_amdgcn_sched_barrier(0)
#define VMC(n) asm volatile("s_waitcnt vmcnt(" #n ")" ::: "memory")
#define LGKM(n) asm volatile("s_waitcnt lgkmcnt(" #n ")" ::: "memory")
#define PRIO1 __builtin_amdgcn_s_setprio(1)
#define PRIO0 __builtin_amdgcn_s_setprio(0)

#define READ_A(qm, bufc) \
  _Pragma("unroll") for (int m_ = 0; m_ < 4; ++m_) { \
    const char* p_ = (bufc) + aOff + (qm) * 8192 + m_ * 2048; \
    aF[m_][0] = *(const bf16x8*)(p_ + sg0); \
    aF[m_][1] = *(const bf16x8*)(p_ + sg1); \
  }

#define READ_B(qn, bufc, DST) \
  _Pragma("unroll") for (int n_ = 0; n_ < 2; ++n_) { \
    const char* p_ = (bufc) + 32768 + bOff + (qn) * 4096 + n_ * 2048; \
    DST[n_][0] = *(const bf16x8*)(p_ + sg0); \
    DST[n_][1] = *(const bf16x8*)(p_ + sg1); \
  }

#define MFMA_Q(qm, qn, BQ) \
  _Pragma("unroll") for (int ks_ = 0; ks_ < 2; ++ks_) \
    _Pragma("unroll") for (int m_ = 0; m_ < 4; ++m_) \
      _Pragma("unroll") for (int n_ = 0; n_ < 2; ++n_) \
        acc[(qm)*4+m_][(qn)*2+n_] = __builtin_amdgcn_mfma_f32_16x16x32_bf16( \
            aF[m_][ks_], BQ[n_][ks_], acc[(qm)*4+m_][(qn)*2+n_], 0, 0, 0);

#define STAGE_A(bufc, kt, ha) \
  _Pragma("unroll") for (int j_ = 0; j_ < 2; ++j_) { \
    int rl_ = (ha) * 128 + (w * 2 + j_) * 8 + stSub; \
    int gr_ = aRow0 + rl_; if (gr_ > Mm1) gr_ = Mm1; \
    __builtin_amdgcn_global_load_lds( \
      (const __attribute__((address_space(1))) void*)(Ap + (long long)gr_ * lda + (kt) * 64 + stSeg8), \
      (__attribute__((address_space(3))) void*)((bufc) + (ha) * 16384 + (w * 2 + j_) * 1024), \
      16, 0, 0); \
  }

#define STAGE_B(bufc, kt, ha) \
  _Pragma("unroll") for (int j_ = 0; j_ < 2; ++j_) { \
    int rl_ = (ha) * 128 + (w * 2 + j_) * 8 + stSub; \
    int gr_ = bRow0 + rl_; \
    __builtin_amdgcn_global_load_lds( \
      (const __attribute__((address_space(1))) void*)(Bp + (long long)gr_ * ldb + (kt) * 64 + stSeg8), \
      (__attribute__((address_space(3))) void*)((bufc) + 32768 + (ha) * 16384 + (w * 2 + j_) * 1024), \
      16, 0, 0); \
  }

template<bool OUT_BF16>
__global__ __launch_bounds__(512, 2)
void k_gemm256(const unsigned short* __restrict__ A,   // [M,K] bf16 (stride lda)
               const unsigned short* __restrict__ B,   // [N,K] bf16 (stride ldb)
               const float* __restrict__ bias,         // [N]
               void* __restrict__ C,                   // [M,N] f32 or bf16 (+ z*M*N)
               int M, int N, int K, int lda, int ldb)
{
  __shared__ __align__(16) char lds[131072];   // 2 x (A 32KB + B 32KB)

  const int tid  = threadIdx.x;
  const int lane = tid & 63;
  const int w    = tid >> 6;       // 0..7
  const int wr   = w >> 2;         // 0..1  (M)
  const int wc   = w & 3;          // 0..3  (N)

  // K-split
  const int z  = blockIdx.z;
  const int Kl = K / gridDim.z;
  const unsigned short* Ap = A + (long long)z * Kl;
  const unsigned short* Bp = B + (long long)z * Kl;
  char* Cz = (char*)C + (long long)z * M * N * (OUT_BF16 ? 2 : 4);

  // grid mapping: bn-chunk per XCD if possible, else m204 bijective swizzle
  const int nwg  = gridDim.x * gridDim.y;
  const int orig = blockIdx.y * gridDim.x + blockIdx.x;
  int bn, bm;
  if ((gridDim.x & 7) == 0 && (nwg & 7) == 0) {
    const int xcd = orig & 7;
    const int j   = orig >> 3;
    const int chunk = gridDim.x >> 3;
    bn = xcd * chunk + (j % chunk);
    bm = j / chunk;
  } else {
    const int q = nwg >> 3, r = nwg & 7;
    const int xcd = orig & 7, land = orig >> 3;
    const int nid = (xcd < r ? xcd * (q + 1) : r * (q + 1) + (xcd - r) * q) + land;
    bn = nid % gridDim.x;
    bm = nid / gridDim.x;
  }

  // per-lane constants
  const int lm = lane & 15;
  const int lk = lane >> 4;                       // 0..3
  const int l7 = lane & 7;
  const int sg0 = ((lk    ) ^ l7) * 16;           // swizzled seg byte off, ks=0
  const int sg1 = ((lk + 4) ^ l7) * 16;           // ks=1
  const int aOff = (wr * 128 + lm) * 128;         // A read base (bytes)
  const int bOff = (wc * 64  + lm) * 128;         // B read base (bytes)
  const int stSub  = lane >> 3;                   // 0..7
  const int stSeg8 = ((lane & 7) ^ stSub) * 8;    // pre-swizzled source seg (elems)
  const int aRow0 = bm * 256;
  const int bRow0 = bn * 256;
  const int Mm1 = M - 1;

  char* lb0 = (char*)lds;            // even K-tiles
  char* lb1 = (char*)lds + 65536;    // odd K-tiles

  f32x4 acc[8][4] = {};
  bf16x8 aF[4][2], bF0[2][2], bF1[2][2];

  const int nkt = Kl >> 6;           // 64-wide K tiles (may be odd; tail below)
  const int nit = nkt >> 1;

  // prologue: tile0 full + tile1.A0
  STAGE_A(lb0, 0, 0); STAGE_A(lb0, 0, 1); STAGE_B(lb0, 0, 0); STAGE_B(lb0, 0, 1);
  STAGE_A(lb1, 1, 0);
  VMC(2);
  SBAR;

  for (int i = 0; i < nit; ++i) {
    const int ktO = 2 * i + 1;
    int ktE2 = 2 * i + 2; if (ktE2 >= nkt) ktE2 = nkt - 1;  // clamped junk on last iter (even nkt)
    int ktO2 = 2 * i + 3; if (ktO2 >= nkt) ktO2 = nkt - 1;
    // P1: tile E quad(0,0)  [12 reads -> lgkm(8) smoothing]
    READ_A(0, lb0); READ_B(0, lb0, bF0);
    STAGE_A(lb1, ktO, 1);
    LGKM(8); SBAR; LGKM(0); SCHB; PRIO1; MFMA_Q(0, 0, bF0); PRIO0; SCHB; SBAR;
    // P2: quad(0,1)
    READ_B(1, lb0, bF1);
    STAGE_B(lb1, ktO, 0);
    SBAR; LGKM(0); SCHB; PRIO1; MFMA_Q(0, 1, bF1); PRIO0; SCHB; SBAR;
    // P3: quad(1,1)
    READ_A(1, lb0);
    STAGE_B(lb1, ktO, 1);
    SBAR; LGKM(0); SCHB; PRIO1; MFMA_Q(1, 1, bF1); PRIO0; SCHB; SBAR;
    // P4: quad(1,0); VMC(2) completes tile O staging
    STAGE_A(lb0, ktE2, 0);
    SBAR; PRIO1; MFMA_Q(1, 0, bF0); PRIO0; SCHB; VMC(2); SBAR;
    // P5: tile O quad(0,0)
    READ_A(0, lb1); READ_B(0, lb1, bF0);
    STAGE_A(lb0, ktE2, 1);
    LGKM(8); SBAR; LGKM(0); SCHB; PRIO1; MFMA_Q(0, 0, bF0); PRIO0; SCHB; SBAR;
    // P6: quad(0,1)
    READ_B(1, lb1, bF1);
    STAGE_B(lb0, ktE2, 0);
    SBAR; LGKM(0); SCHB; PRIO1; MFMA_Q(0, 1, bF1); PRIO0; SCHB; SBAR;
    // P7: quad(1,1)
    READ_A(1, lb1);
    STAGE_B(lb0, ktE2, 1);
    SBAR; LGKM(0); SCHB; PRIO1; MFMA_Q(1, 1, bF1); PRIO0; SCHB; SBAR;
    // P8: quad(1,0); VMC(2) completes tile E' staging
    STAGE_A(lb1, ktO2, 0);
    SBAR; PRIO1; MFMA_Q(1, 0, bF0); PRIO0; SCHB; VMC(2); SBAR;
  }

  // odd-tail: tile nkt-1 (even index -> lb0) was staged at P4..P7 of the last
  // iteration and fully drained by P8's VMC(2); all waves synced at P8's SBAR.
  // No further LDS writes -> barrier-free; compiler inserts lgkm waits.
  if (nkt & 1) {
    READ_A(0, lb0); READ_B(0, lb0, bF0); READ_B(1, lb0, bF1);
    MFMA_Q(0, 0, bF0); MFMA_Q(0, 1, bF1);
    READ_A(1, lb0);
    MFMA_Q(1, 1, bF1); MFMA_Q(1, 0, bF0);
  }

  // epilogue: C[row, col] = acc + bias
#pragma unroll
  for (int in = 0; in < 4; ++in) {
    const int col = bn * 256 + wc * 64 + in * 16 + lm;
    const float bv = bias[col];
#pragma unroll
    for (int im = 0; im < 8; ++im) {
      const int row0 = bm * 256 + wr * 128 + im * 16 + lk * 4;
#pragma unroll
      for (int jj = 0; jj < 4; ++jj) {
        const int row = row0 + jj;
        if (row < M) {
          const float v = acc[im][in][jj] + bv;
          if (OUT_BF16)
            __builtin_nontemporal_store(f2bf(v), &((unsigned short*)Cz)[(long long)row * N + col]);
          else
            __builtin_nontemporal_store(v, &((float*)Cz)[(long long)row * N + col]);
        }
      }
    }
  }
}

extern "C" void kernel_launch(void* const* d_in, const int* in_sizes, int n_in,
                              void* d_out, int out_size, void* d_ws, size_t ws_size,
                              hipStream_t stream) {
  const float* x  = (const float*)d_in[0];
  const int*   ei = (const int*)d_in[1];      // int32 or int64 — detected on device
  const float* W1 = (const float*)d_in[2];
  const float* b1 = (const float*)d_in[3];
  const float* W2 = (const float*)d_in[4];
  const float* b2 = (const float*)d_in[5];
  float* out = (float*)d_out;
  char* ws = (char*)d_ws;

  // workspace layout (bytes, 16B-aligned)
  int* flag            = (int*)(ws + 0);                     // 256
  int* deg             = (int*)(ws + 256);                   // 80,000
  int* offs            = (int*)(ws + 80256);                 // 80,000
  int* cursor          = (int*)(ws + 160256);                // 80,000
  int* csr             = (int*)(ws + 240256);                // 2,560,000
  unsigned short* xb   = (unsigned short*)(ws + 2800256);    // 20,480,000
  unsigned short* hb   = (unsigned short*)(ws + 23280256);   // 20,480,000
  unsigned short* w1t  = (unsigned short*)(ws + 43760256);   //  4,456,448  [HID x MID]
  unsigned short* w2b  = (unsigned short*)(ws + 48216704);   // 71,303,168
  float*          wcp  = (float*)(ws + 119519872);           // 4 x 16,777,216 (K-split partials)
  unsigned short* wcb  = (unsigned short*)(ws + 186628736);  //  8,388,608  [VOC x HID]
  float*          b2p  = (float*)(ws + 195017344);           //     32,768
  float*          zb   = (float*)(ws + 195050112);           //      2,048  (zero bias)
  if (ws_size < 195052160ULL) return;

  // 0) detect edge_index width
  k_detect64<<<1, 256, 0, stream>>>(ei, flag);

  // 1) CSR build (+ zero the zero-bias)
  k_zero_i32<<<(NN + 255) / 256, 256, 0, stream>>>(deg, NN);
  k_zero_i32<<<2, 256, 0, stream>>>((int*)zb, 512);
  k_count<<<(NE + 255) / 256, 256, 0, stream>>>(ei, flag, deg);
  k_scan<<<1, 1024, 0, stream>>>(deg, offs, cursor);
  k_fill<<<(NE + 255) / 256, 256, 0, stream>>>(ei, flag, cursor, csr);

  // 2) conversions: x -> xb (gather needs it); W2 -> w2b fused with b2' dot;
  //    W1 -> w1t (transposed)
  k_f32_to_bf16<<<2048, 256, 0, stream>>>((const float4*)x, (uint2*)xb, NN * HID / 4);
  k_w2_cvt_bias<<<VOC, 256, 0, stream>>>((const float4*)W2, (const float4*)b1, b2,
                                         (uint2*)w2b, b2p);
  {
    dim3 gt(HID / 64, MID / 64);   // (8, 68)
    k_transpose_cvt<<<gt, 256, 0, stream>>>(W1, w1t);
  }

  // 3) fused gather: hb = bf16(x_i + sum_j bf16(x_j))
  k_gather2<<<(NN + 3) / 4, 256, 0, stream>>>((const float4*)x, (const uint4*)xb,
                                              offs, deg, csr, (uint4*)hb);

  // 4) Wc = W2 @ W1 : [VOC, HID], K=MID split in 4 (17 tiles each, odd-tail path),
  //    f32 partials, then combine -> bf16
  {
    dim3 g(HID / 256, VOC / 256, 4);   // (2, 32, 4) = 256 blocks
    k_gemm256<false><<<g, 512, 0, stream>>>(w2b, w1t, zb, (void*)wcp,
                                            VOC, HID, MID, MID, MID);
    k_combine4<<<1024, 256, 0, stream>>>((const float4*)wcp, (uint2*)wcb, VOC * HID / 4);
  }

  // 5) out = hb @ Wc^T + b2' : [NN, VOC], K=HID
  {
    dim3 g(VOC / 256, (NN + 255) / 256, 1);   // (32, 79)
    k_gemm256<false><<<g, 512, 0, stream>>>(hb, wcb, b2p, (void*)out,
                                            NN, VOC, HID, HID, HID);
  }
}